// Round 6
// baseline (3052.984 us; speedup 1.0000x reference)
//
#include <hip/hip_runtime.h>

#define HID 256
#define AS_LD 72    // u16; K-loop A-tile row stride (144 B)
#define TB_LD 264   // u16; epilogue transpose row stride (528 B, 16B-aligned)

typedef unsigned short u16;
typedef unsigned char u8;
typedef unsigned int u32;
typedef short bf16x8 __attribute__((ext_vector_type(8)));
typedef float f32x4 __attribute__((ext_vector_type(4)));
typedef u16 u16x8 __attribute__((ext_vector_type(8)));
typedef u8 u8x8 __attribute__((ext_vector_type(8)));

static __device__ __forceinline__ float bf2f(u16 b) {
    u32 u = ((u32)b) << 16;
    return __uint_as_float(u);
}
static __device__ __forceinline__ u16 f2bf(float f) {
    u32 u = __float_as_uint(f);
    return (u16)((u + 0x7FFFu + ((u >> 16) & 1u)) >> 16);  // RN-even
}

// ---------------------------------------------------------------------------
// Fused gather + GEMM + relu, tile 64 rows x 256 cols, BK=64, 512 threads.
// R6: message buffers are U8 + per-(row, 64-col-chunk) fp32 scale.
//   Messages are relu outputs (>=0); linear quant q = round(v * 255/chunkmax),
//   dequant v = q * s (s = chunkmax/255). Quant noise ~0.5% of activation RMS
//   (~2x bf16 rounding, vs fp8-e4m3's ~8x) and the gather sum is exact-linear
//   in the dequant: sum_j s_j * q_j.
//   Effect: gather demand 614 -> 326 MB/layer; working set 230 -> 134 MB
//   (52% of L3 instead of 90% -> less thrash on top of byte halving).
// Pipeline per chunk kc (issue-order discipline, R3):
//   1. bq loads (WB B-frags, L2-hot)   <- oldest this iteration
//   2. consume(kc): vmcnt waits for gather kc only (bq in flight);
//      dequant-sum 6 u8x8 * scale -> bf16 -> LDS (double-buffered A-tile)
//   3. issue(kc+1) gathers (+scales)   <- youngest, span barrier+compute
//   4. s_waitcnt lgkmcnt(0) + raw s_barrier (no vmcnt drain)
//   5. ds_read af + 16 MFMAs (bq wait = counted vmcnt)
// Epilogue: pass-1 LDS transpose (unchanged); pass-2 either bf16 store
// (Csc==nullptr; output layer) or u8 quant store: 8-lane shfl-max per
// 64-col chunk -> scale -> packed u8x8 store + one scale store per chunk.
// launch_bounds (512,4): VGPR cap 128 (R4 lesson: (512,6) caps at 40 and
// spills acc+prefetch state -> 1.4 GB scratch traffic).
// ---------------------------------------------------------------------------
__global__ __launch_bounds__(512, 4) void fused_layer(
    const u8* __restrict__ Sg, const float* __restrict__ Ssc,
    const int* __restrict__ graph, int c1,
    const u16* __restrict__ Bd, int ldbd, int c2,
    const float* __restrict__ Cf, int ldcf, int Kc, int c3,
    const u16* __restrict__ WB, int ldw,
    const float* __restrict__ bias,
    void* __restrict__ Cout, float* __restrict__ Csc, int M)
{
    __shared__ __align__(16) u16 lds[2 * 64 * AS_LD];   // 18,432 B (union: A-dbuf / transpose)

    const int t    = threadIdx.x;
    const int w    = t >> 6;           // 0..7
    const int lane = t & 63;
    const int row0 = blockIdx.x * 64;
    const int wc   = w * 32;           // wave's 32 columns
    const int fr   = lane & 15;
    const int fq   = lane >> 4;

    const int g  = t & 7;              // 8B/16B granule within row-chunk
    const int ra = t >> 3;             // 0..63 -> one row per thread
    const int gr = row0 + ra;
    const int grc = gr < M ? gr : 0;

    int nbi[6];
    const u16* bdp = nullptr;
    if (c1 > 0) {
        const int* gp = graph + (size_t)grc * 6;
        #pragma unroll
        for (int j = 0; j < 6; ++j) nbi[j] = gp[j];
    }
    if (c2 > 0) bdp = Bd + (size_t)grc * ldbd;

    const int nch = c1 + c2 + c3;
    const int nbf = c1 + c2;           // gather + direct-bf16 chunks

    // prefetch registers (chunk kc in flight while chunk kc-1 computes)
    u8x8  va[6];                       // u8 gather rows
    float sv[6];                       // their dequant scales
    u16x8 vb;                          // direct bf16 chunk
    float fa[8];                       // fp32 chunk

    // issue global loads for chunk kc (register destinations, non-blocking)
    auto issue = [&](int kc) {
        if (kc < c1) {
            #pragma unroll
            for (int j = 0; j < 6; ++j)
                va[j] = *(const u8x8*)(Sg + (size_t)nbi[j] * 256 + kc * 64 + g * 8);
            #pragma unroll
            for (int j = 0; j < 6; ++j)
                sv[j] = Ssc[(size_t)nbi[j] * 4 + kc];
        } else if (kc < nbf) {
            vb = *(const u16x8*)(bdp + (kc - c1) * 64 + g * 8);
        } else {
            const int kb = (kc - nbf) * 64 + g * 8;
            #pragma unroll
            for (int i = 0; i < 8; ++i)
                fa[i] = (gr < M && kb + i < Kc) ? Cf[(size_t)gr * ldcf + kb + i] : 0.f;
        }
    };

    // consume in-flight loads for chunk kc -> bf16 row fragment -> LDS
    auto consume = [&](int kc, u16* Ab) {
        u16 o[8];
        if (kc < c1) {
            float sa[8] = {};
            #pragma unroll
            for (int j = 0; j < 6; ++j)
                #pragma unroll
                for (int e = 0; e < 8; ++e) sa[e] += (float)va[j][e] * sv[j];
            #pragma unroll
            for (int e = 0; e < 8; ++e) o[e] = f2bf(sa[e]);
        } else if (kc < nbf) {
            *(u16x8*)o = vb;
        } else {
            #pragma unroll
            for (int i = 0; i < 8; ++i) o[i] = f2bf(fa[i]);
        }
        *(uint4*)(Ab + ra * AS_LD + g * 8) = *(const uint4*)o;
    };

    f32x4 acc[4][2] = {};
    issue(0);
    #pragma unroll 1
    for (int kc = 0; kc < nch; ++kc) {
        u16* Ab = lds + (kc & 1) * (64 * AS_LD);

        // 1. B fragments for this chunk FIRST (older than the prefetch, so
        //    the compute phase needs only a counted vmcnt wait for them)
        bf16x8 bq[2][2];
        #pragma unroll
        for (int s = 0; s < 2; ++s)
            #pragma unroll
            for (int j = 0; j < 2; ++j) {
                const int col = wc + j * 16 + fr;
                bq[s][j] = *(const bf16x8*)(WB + (size_t)col * ldw + kc * 64 + s * 32 + fq * 8);
            }

        // 2. consume chunk kc (waits for its gathers; bq still in flight)
        consume(kc, Ab);

        // 3. prefetch chunk kc+1 (youngest; stays outstanding across
        //    barrier + compute + next iteration's bq/consume)
        if (kc + 1 < nch) issue(kc + 1);

        // 4. drain LDS writes only; global prefetch stays outstanding
        asm volatile("s_waitcnt lgkmcnt(0)" ::: "memory");
        __builtin_amdgcn_s_barrier();
        asm volatile("" ::: "memory");   // fence: no memory-op hoist above barrier

        // 5. compute: ds_read A frags + 16 MFMAs (bq wait = counted vmcnt)
        #pragma unroll
        for (int s = 0; s < 2; ++s) {
            bf16x8 af[4];
            #pragma unroll
            for (int i = 0; i < 4; ++i)
                af[i] = *(const bf16x8*)(Ab + (i * 16 + fr) * AS_LD + s * 32 + fq * 8);
            #pragma unroll
            for (int j = 0; j < 2; ++j)
                #pragma unroll
                for (int i = 0; i < 4; ++i)
                    acc[i][j] = __builtin_amdgcn_mfma_f32_16x16x32_bf16(bq[s][j], af[i], acc[i][j], 0, 0, 0);
        }
    }

    // ---- epilogue: 2-pass transpose through LDS ----
    // acc[i][j]: C-rows i*16+fr, C-cols wc + j*16 + fq*4 .. +3
    u16* Tb = lds;                          // 32 x TB_LD view
    const bool quant = (Csc != nullptr);
    #pragma unroll
    for (int s2 = 0; s2 < 2; ++s2) {
        __syncthreads();                    // K-loop / previous pass done with lds
        #pragma unroll
        for (int j = 0; j < 2; ++j) {
            const int gc = wc + j * 16 + fq * 4;
            float4 bv = make_float4(0.f, 0.f, 0.f, 0.f);
            if (bias) bv = *(const float4*)&bias[gc];
            #pragma unroll
            for (int ii = 0; ii < 2; ++ii) {
                const int i = s2 * 2 + ii;  // acc row-block
                u16 o[4];
                o[0] = f2bf(fmaxf(acc[i][j][0] + bv.x, 0.f));
                o[1] = f2bf(fmaxf(acc[i][j][1] + bv.y, 0.f));
                o[2] = f2bf(fmaxf(acc[i][j][2] + bv.z, 0.f));
                o[3] = f2bf(fmaxf(acc[i][j][3] + bv.w, 0.f));
                *(uint2*)(Tb + (ii * 16 + fr) * TB_LD + gc) = *(const uint2*)o;
            }
        }
        __syncthreads();                    // half-tile complete
        const int gsl = t & 31;             // 8-col granule within 256-col row
        const int rb  = t >> 5;             // 0..15
        #pragma unroll
        for (int it2 = 0; it2 < 2; ++it2) {
            const int rl = it2 * 16 + rb;
            const int grr = row0 + s2 * 32 + rl;
            const u16x8 v = *(const u16x8*)(Tb + rl * TB_LD + gsl * 8);
            if (quant) {
                // per-(row, 64-col-chunk) linear quant; chunk = gsl>>3,
                // 8-lane shfl-max within the chunk's granule group
                float f[8];
                float mx = 0.f;
                #pragma unroll
                for (int e = 0; e < 8; ++e) { f[e] = bf2f(v[e]); mx = fmaxf(mx, f[e]); }
                mx = fmaxf(mx, __shfl_xor(mx, 1));
                mx = fmaxf(mx, __shfl_xor(mx, 2));
                mx = fmaxf(mx, __shfl_xor(mx, 4));
                const float r = mx > 0.f ? 255.f / mx : 0.f;
                u8x8 q;
                #pragma unroll
                for (int e = 0; e < 8; ++e) q[e] = (u8)(f[e] * r + 0.5f);
                if (grr < M) {
                    *(u8x8*)((u8*)Cout + (size_t)grr * 256 + gsl * 8) = q;
                    if ((gsl & 7) == 0)
                        Csc[(size_t)grr * 4 + (gsl >> 3)] = mx * (1.f / 255.f);
                }
            } else {
                if (grr < M)
                    *(u16x8*)((u16*)Cout + (size_t)grr * 256 + gsl * 8) = v;
            }
        }
    }
}

// WB[n][k] bf16: k<k1 -> src1[n][off1+k]; k1<=k<k1+k2 -> src2[n][off2+k-k1]; else 0
__global__ void build_wb(const float* __restrict__ src1, int lds1, int off1, int k1,
                         const float* __restrict__ src2, int lds2, int off2, int k2,
                         u16* __restrict__ dst, int ldd)
{
    const int n = blockIdx.x;  // 0..255
    for (int k = threadIdx.x; k < ldd; k += blockDim.x) {
        float v = 0.f;
        if (k < k1)           v = src1[(size_t)n * lds1 + off1 + k];
        else if (k < k1 + k2) v = src2[(size_t)n * lds2 + off2 + (k - k1)];
        dst[(size_t)n * ldd + k] = f2bf(v);
    }
}

// FB[e][0:64] = bf16(fbonds[e][0:50]) padded with zeros
__global__ void build_fb(const float* __restrict__ fb, u16* __restrict__ FB, int E)
{
    const int e = blockIdx.x * 4 + (threadIdx.x >> 6);
    if (e >= E) return;
    const int k = threadIdx.x & 63;
    FB[(size_t)e * 64 + k] = (k < 50) ? f2bf(fb[(size_t)e * 50 + k]) : (u16)0;
}

// per-molecule mean over sorted mol_ids; atomh bf16, out fp32
__global__ void segment_mean(const u16* __restrict__ atomh, const int* __restrict__ mol_ids,
                             float* __restrict__ out, int N)
{
    const int m = blockIdx.x;
    const int t = threadIdx.x;
    __shared__ int s_lo, s_hi;
    if (t == 0) {
        int lo = 0, hi = N;
        while (lo < hi) { int mid = (lo + hi) >> 1; if (mol_ids[mid] < m) lo = mid + 1; else hi = mid; }
        s_lo = lo;
        lo = s_lo; hi = N;
        while (lo < hi) { int mid = (lo + hi) >> 1; if (mol_ids[mid] < m + 1) lo = mid + 1; else hi = mid; }
        s_hi = lo;
    }
    __syncthreads();
    const int lo = s_lo, hi = s_hi;
    float sum = 0.f;
    for (int a = lo; a < hi; ++a) sum += bf2f(atomh[(size_t)a * HID + t]);
    const float cnt = (float)((hi - lo) > 1 ? (hi - lo) : 1);
    out[(size_t)m * HID + t] = sum / cnt;
}

extern "C" void kernel_launch(void* const* d_in, const int* in_sizes, int n_in,
                              void* d_out, int out_size, void* d_ws, size_t ws_size,
                              hipStream_t stream)
{
    const float* fatoms = (const float*)d_in[0];
    const float* fbonds = (const float*)d_in[1];
    const int*   agraph = (const int*)d_in[2];
    const int*   bgraph = (const int*)d_in[3];
    const int*   mol_ids = (const int*)d_in[4];
    const float* W_i = (const float*)d_in[7];
    const float* W_h = (const float*)d_in[8];
    const float* W_o = (const float*)d_in[9];
    const float* b_o = (const float*)d_in[10];

    const int N = in_sizes[0] / 39;       // 100000
    const int E = in_sizes[1] / 50;       // 200001
    const int N_MOLS = 1000;
    const int DEPTH = 6;

    // workspace layout (bytes); all section sizes are multiples of 16
    const size_t q_sz  = (size_t)E * 256;            // u8 messages [E][256]
    const size_t sc_sz = (size_t)E * 4 * 4;          // fp32 scales [E][4]
    const size_t fb_sz = (size_t)E * 64 * 2;         // bf16 FB [E][64]
    const size_t ah_sz = (size_t)N * HID * 2;        // bf16 atom_hiddens [N][256]
    const size_t wbh_sz = (size_t)256 * 320 * 2;
    const size_t wbi_sz = (size_t)256 * 64 * 2;
    const size_t wbo_sz = (size_t)256 * 320 * 2;
    const size_t need = 2 * q_sz + 2 * sc_sz + fb_sz + ah_sz + wbh_sz + wbi_sz + wbo_sz;
    if (ws_size < need) return;

    u8* p = (u8*)d_ws;
    u8*    q0  = p;             p += q_sz;
    u8*    q1  = p;             p += q_sz;
    float* sc0 = (float*)p;     p += sc_sz;
    float* sc1 = (float*)p;     p += sc_sz;
    u16*   FB  = (u16*)p;       p += fb_sz;
    u16*   ah  = (u16*)p;       p += ah_sz;
    u16*   wbh = (u16*)p;       p += wbh_sz;
    u16*   wbi = (u16*)p;       p += wbi_sz;
    u16*   wbo = (u16*)p;

    float* out = (float*)d_out;

    build_wb<<<dim3(256), dim3(64), 0, stream>>>(W_h, 256, 0, 256, W_i, 50, 0, 50, wbh, 320);
    build_wb<<<dim3(256), dim3(64), 0, stream>>>(W_i, 50, 0, 50, W_i, 50, 0, 0, wbi, 64);
    build_wb<<<dim3(256), dim3(64), 0, stream>>>(W_o, 295, 39, 256, W_o, 295, 0, 39, wbo, 320);
    build_fb<<<dim3((E + 3) / 4), dim3(256), 0, stream>>>(fbonds, FB, E);

    const int gE = (E + 63) / 64;     // 3126
    const int gN = (N + 63) / 64;     // 1563

    // layer 0: q0 = quant(relu(FB @ W_i.T))
    fused_layer<<<dim3(gE), dim3(512), 0, stream>>>(
        nullptr, nullptr, nullptr, 0, FB, 64, 1, nullptr, 0, 0, 0,
        wbi, 64, nullptr, q0, sc0, E);

    // hidden layers (ping-pong): dst = quant(relu(gather(src)@W_h.T + fbonds@W_i.T))
    u8* src = q0;  float* ssc = sc0;
    u8* dst = q1;  float* dsc = sc1;
    for (int it = 0; it < DEPTH - 1; ++it) {
        fused_layer<<<dim3(gE), dim3(512), 0, stream>>>(
            src, ssc, bgraph, 4, FB, 64, 1, nullptr, 0, 0, 0,
            wbh, 320, nullptr, dst, dsc, E);
        u8* tq = src; src = dst; dst = tq;
        float* ts = ssc; ssc = dsc; dsc = ts;
    }
    // after 5 layers: src = q1/sc1 (final message)

    // output layer: ah = relu(gather_a(src)@W_o[:,39:].T + fatoms@W_o[:,:39].T + b_o), bf16
    fused_layer<<<dim3(gN), dim3(512), 0, stream>>>(
        src, ssc, agraph, 4, nullptr, 0, 0, fatoms, 39, 39, 1,
        wbo, 320, b_o, ah, nullptr, N);

    // per-molecule mean
    segment_mean<<<dim3(N_MOLS), dim3(256), 0, stream>>>(ah, mol_ids, out, N);
}

// Round 7
// 1308.195 us; speedup vs baseline: 2.3337x; 2.3337x over previous
//
#include <hip/hip_runtime.h>

#define HID 256
#define AS_LD 72    // u16; K-loop A-tile row stride (144 B)
#define TB_LD 264   // u16; epilogue transpose row stride (528 B, 16B-aligned)

typedef unsigned short u16;
typedef unsigned char u8;
typedef unsigned int u32;
typedef short bf16x8 __attribute__((ext_vector_type(8)));
typedef float f32x4 __attribute__((ext_vector_type(4)));
typedef u16 u16x8 __attribute__((ext_vector_type(8)));

static __device__ __forceinline__ float bf2f(u16 b) {
    u32 u = ((u32)b) << 16;
    return __uint_as_float(u);
}
static __device__ __forceinline__ u16 f2bf(float f) {
    u32 u = __float_as_uint(f);
    return (u16)((u + 0x7FFFu + ((u >> 16) & 1u)) >> 16);  // RN-even
}

// ---------------------------------------------------------------------------
// Fused gather + GEMM + relu, tile 64 rows x 256 cols, BK=64, 512 threads.
// R7: same u8-quantized message scheme as R6 (numerics validated: passed),
// recoded to avoid the R6 scratch spill (WRITE_SIZE 923 MB signature):
//   - gather loads are uint2 (2 dwords), bytes extracted via shift/mask
//     (-> v_cvt_f32_ubyte0..3), accumulated per-neighbor sequentially so
//     the transient window is ~3 regs instead of 48 hoisted byte values
//   - epilogue packs quantized bytes into two u32s (no u8 vectors anywhere)
// Messages: u8 + per-(row, 64-col-chunk) fp32 scale. q = round(v*255/max),
// dequant sum = sum_j s_j * q_j (exact-linear). Noise ~0.5% of act RMS.
// Bytes: gather demand 614 -> 326 MB/layer; WS 230 -> 134 MB (L3-friendly).
// Pipeline per chunk kc (issue-order discipline, R3):
//   1. bq loads (WB B-frags, L2-hot)   <- oldest this iteration
//   2. consume(kc): vmcnt waits for gather kc only (bq in flight)
//   3. issue(kc+1) gathers (+scales)   <- youngest, span barrier+compute
//   4. s_waitcnt lgkmcnt(0) + raw s_barrier (no vmcnt drain)
//   5. ds_read af + 16 MFMAs (bq wait = counted vmcnt)
// launch_bounds (512,4): VGPR cap 128 (R4 lesson: (512,6) caps at 40 ->
// 1.4 GB scratch traffic; R6 lesson: transient pressure spills too).
// ---------------------------------------------------------------------------
__global__ __launch_bounds__(512, 4) void fused_layer(
    const u8* __restrict__ Sg, const float* __restrict__ Ssc,
    const int* __restrict__ graph, int c1,
    const u16* __restrict__ Bd, int ldbd, int c2,
    const float* __restrict__ Cf, int ldcf, int Kc, int c3,
    const u16* __restrict__ WB, int ldw,
    const float* __restrict__ bias,
    void* __restrict__ Cout, float* __restrict__ Csc, int M)
{
    __shared__ __align__(16) u16 lds[2 * 64 * AS_LD];   // 18,432 B (union: A-dbuf / transpose)

    const int t    = threadIdx.x;
    const int w    = t >> 6;           // 0..7
    const int lane = t & 63;
    const int row0 = blockIdx.x * 64;
    const int wc   = w * 32;           // wave's 32 columns
    const int fr   = lane & 15;
    const int fq   = lane >> 4;

    const int g  = t & 7;              // 8B/16B granule within row-chunk
    const int ra = t >> 3;             // 0..63 -> one row per thread
    const int gr = row0 + ra;
    const int grc = gr < M ? gr : 0;

    int nbi[6];
    const u16* bdp = nullptr;
    if (c1 > 0) {
        const int* gp = graph + (size_t)grc * 6;
        #pragma unroll
        for (int j = 0; j < 6; ++j) nbi[j] = gp[j];
    }
    if (c2 > 0) bdp = Bd + (size_t)grc * ldbd;

    const int nch = c1 + c2 + c3;
    const int nbf = c1 + c2;           // gather + direct-bf16 chunks

    // prefetch registers (chunk kc in flight while chunk kc-1 computes)
    uint2 va[6];                       // u8 gather rows (2 dwords each)
    float sv[6];                       // their dequant scales
    u16x8 vb;                          // direct bf16 chunk
    float fa[8];                       // fp32 chunk

    // issue global loads for chunk kc (register destinations, non-blocking)
    auto issue = [&](int kc) {
        if (kc < c1) {
            #pragma unroll
            for (int j = 0; j < 6; ++j)
                va[j] = *(const uint2*)(Sg + (size_t)nbi[j] * 256 + kc * 64 + g * 8);
            #pragma unroll
            for (int j = 0; j < 6; ++j)
                sv[j] = Ssc[(size_t)nbi[j] * 4 + kc];
        } else if (kc < nbf) {
            vb = *(const u16x8*)(bdp + (kc - c1) * 64 + g * 8);
        } else {
            const int kb = (kc - nbf) * 64 + g * 8;
            #pragma unroll
            for (int i = 0; i < 8; ++i)
                fa[i] = (gr < M && kb + i < Kc) ? Cf[(size_t)gr * ldcf + kb + i] : 0.f;
        }
    };

    // consume in-flight loads for chunk kc -> bf16 row fragment -> LDS
    auto consume = [&](int kc, u16* Ab) {
        u16 o[8];
        if (kc < c1) {
            float sa[8] = {};
            #pragma unroll
            for (int j = 0; j < 6; ++j) {
                const u32 lo = va[j].x, hi = va[j].y;
                const float s = sv[j];
                sa[0] += (float)( lo        & 0xFFu) * s;
                sa[1] += (float)((lo >>  8) & 0xFFu) * s;
                sa[2] += (float)((lo >> 16) & 0xFFu) * s;
                sa[3] += (float)( lo >> 24         ) * s;
                sa[4] += (float)( hi        & 0xFFu) * s;
                sa[5] += (float)((hi >>  8) & 0xFFu) * s;
                sa[6] += (float)((hi >> 16) & 0xFFu) * s;
                sa[7] += (float)( hi >> 24         ) * s;
            }
            #pragma unroll
            for (int e = 0; e < 8; ++e) o[e] = f2bf(sa[e]);
        } else if (kc < nbf) {
            *(u16x8*)o = vb;
        } else {
            #pragma unroll
            for (int i = 0; i < 8; ++i) o[i] = f2bf(fa[i]);
        }
        *(uint4*)(Ab + ra * AS_LD + g * 8) = *(const uint4*)o;
    };

    f32x4 acc[4][2] = {};
    issue(0);
    #pragma unroll 1
    for (int kc = 0; kc < nch; ++kc) {
        u16* Ab = lds + (kc & 1) * (64 * AS_LD);

        // 1. B fragments for this chunk FIRST (older than the prefetch, so
        //    the compute phase needs only a counted vmcnt wait for them)
        bf16x8 bq[2][2];
        #pragma unroll
        for (int s = 0; s < 2; ++s)
            #pragma unroll
            for (int j = 0; j < 2; ++j) {
                const int col = wc + j * 16 + fr;
                bq[s][j] = *(const bf16x8*)(WB + (size_t)col * ldw + kc * 64 + s * 32 + fq * 8);
            }

        // 2. consume chunk kc (waits for its gathers; bq still in flight)
        consume(kc, Ab);

        // 3. prefetch chunk kc+1 (youngest; stays outstanding across
        //    barrier + compute + next iteration's bq/consume)
        if (kc + 1 < nch) issue(kc + 1);

        // 4. drain LDS writes only; global prefetch stays outstanding
        asm volatile("s_waitcnt lgkmcnt(0)" ::: "memory");
        __builtin_amdgcn_s_barrier();
        asm volatile("" ::: "memory");   // fence: no memory-op hoist above barrier

        // 5. compute: ds_read A frags + 16 MFMAs (bq wait = counted vmcnt)
        #pragma unroll
        for (int s = 0; s < 2; ++s) {
            bf16x8 af[4];
            #pragma unroll
            for (int i = 0; i < 4; ++i)
                af[i] = *(const bf16x8*)(Ab + (i * 16 + fr) * AS_LD + s * 32 + fq * 8);
            #pragma unroll
            for (int j = 0; j < 2; ++j)
                #pragma unroll
                for (int i = 0; i < 4; ++i)
                    acc[i][j] = __builtin_amdgcn_mfma_f32_16x16x32_bf16(bq[s][j], af[i], acc[i][j], 0, 0, 0);
        }
    }

    // ---- epilogue: 2-pass transpose through LDS ----
    // acc[i][j]: C-rows i*16+fr, C-cols wc + j*16 + fq*4 .. +3
    u16* Tb = lds;                          // 32 x TB_LD view
    const bool quant = (Csc != nullptr);
    #pragma unroll
    for (int s2 = 0; s2 < 2; ++s2) {
        __syncthreads();                    // K-loop / previous pass done with lds
        #pragma unroll
        for (int j = 0; j < 2; ++j) {
            const int gc = wc + j * 16 + fq * 4;
            float4 bv = make_float4(0.f, 0.f, 0.f, 0.f);
            if (bias) bv = *(const float4*)&bias[gc];
            #pragma unroll
            for (int ii = 0; ii < 2; ++ii) {
                const int i = s2 * 2 + ii;  // acc row-block
                u16 o[4];
                o[0] = f2bf(fmaxf(acc[i][j][0] + bv.x, 0.f));
                o[1] = f2bf(fmaxf(acc[i][j][1] + bv.y, 0.f));
                o[2] = f2bf(fmaxf(acc[i][j][2] + bv.z, 0.f));
                o[3] = f2bf(fmaxf(acc[i][j][3] + bv.w, 0.f));
                *(uint2*)(Tb + (ii * 16 + fr) * TB_LD + gc) = *(const uint2*)o;
            }
        }
        __syncthreads();                    // half-tile complete
        const int gsl = t & 31;             // 8-col granule within 256-col row
        const int rb  = t >> 5;             // 0..15
        #pragma unroll
        for (int it2 = 0; it2 < 2; ++it2) {
            const int rl = it2 * 16 + rb;
            const int grr = row0 + s2 * 32 + rl;
            const u16x8 v = *(const u16x8*)(Tb + rl * TB_LD + gsl * 8);
            if (quant) {
                // per-(row, 64-col-chunk) linear quant; chunk = gsl>>3,
                // 8-lane shfl-max within the chunk's granule group
                float f[8];
                float mx = 0.f;
                #pragma unroll
                for (int e = 0; e < 8; ++e) { f[e] = bf2f(v[e]); mx = fmaxf(mx, f[e]); }
                mx = fmaxf(mx, __shfl_xor(mx, 1));
                mx = fmaxf(mx, __shfl_xor(mx, 2));
                mx = fmaxf(mx, __shfl_xor(mx, 4));
                const float r = mx > 0.f ? 255.f / mx : 0.f;
                u32 plo = 0, phi = 0;
                #pragma unroll
                for (int e = 0; e < 4; ++e)
                    plo |= ((u32)(f[e] * r + 0.5f)) << (8 * e);
                #pragma unroll
                for (int e = 4; e < 8; ++e)
                    phi |= ((u32)(f[e] * r + 0.5f)) << (8 * (e - 4));
                if (grr < M) {
                    uint2 qv; qv.x = plo; qv.y = phi;
                    *(uint2*)((u8*)Cout + (size_t)grr * 256 + gsl * 8) = qv;
                    if ((gsl & 7) == 0)
                        Csc[(size_t)grr * 4 + (gsl >> 3)] = mx * (1.f / 255.f);
                }
            } else {
                if (grr < M)
                    *(u16x8*)((u16*)Cout + (size_t)grr * 256 + gsl * 8) = v;
            }
        }
    }
}

// WB[n][k] bf16: k<k1 -> src1[n][off1+k]; k1<=k<k1+k2 -> src2[n][off2+k-k1]; else 0
__global__ void build_wb(const float* __restrict__ src1, int lds1, int off1, int k1,
                         const float* __restrict__ src2, int lds2, int off2, int k2,
                         u16* __restrict__ dst, int ldd)
{
    const int n = blockIdx.x;  // 0..255
    for (int k = threadIdx.x; k < ldd; k += blockDim.x) {
        float v = 0.f;
        if (k < k1)           v = src1[(size_t)n * lds1 + off1 + k];
        else if (k < k1 + k2) v = src2[(size_t)n * lds2 + off2 + (k - k1)];
        dst[(size_t)n * ldd + k] = f2bf(v);
    }
}

// FB[e][0:64] = bf16(fbonds[e][0:50]) padded with zeros
__global__ void build_fb(const float* __restrict__ fb, u16* __restrict__ FB, int E)
{
    const int e = blockIdx.x * 4 + (threadIdx.x >> 6);
    if (e >= E) return;
    const int k = threadIdx.x & 63;
    FB[(size_t)e * 64 + k] = (k < 50) ? f2bf(fb[(size_t)e * 50 + k]) : (u16)0;
}

// per-molecule mean over sorted mol_ids; atomh bf16, out fp32
__global__ void segment_mean(const u16* __restrict__ atomh, const int* __restrict__ mol_ids,
                             float* __restrict__ out, int N)
{
    const int m = blockIdx.x;
    const int t = threadIdx.x;
    __shared__ int s_lo, s_hi;
    if (t == 0) {
        int lo = 0, hi = N;
        while (lo < hi) { int mid = (lo + hi) >> 1; if (mol_ids[mid] < m) lo = mid + 1; else hi = mid; }
        s_lo = lo;
        lo = s_lo; hi = N;
        while (lo < hi) { int mid = (lo + hi) >> 1; if (mol_ids[mid] < m + 1) lo = mid + 1; else hi = mid; }
        s_hi = lo;
    }
    __syncthreads();
    const int lo = s_lo, hi = s_hi;
    float sum = 0.f;
    for (int a = lo; a < hi; ++a) sum += bf2f(atomh[(size_t)a * HID + t]);
    const float cnt = (float)((hi - lo) > 1 ? (hi - lo) : 1);
    out[(size_t)m * HID + t] = sum / cnt;
}

extern "C" void kernel_launch(void* const* d_in, const int* in_sizes, int n_in,
                              void* d_out, int out_size, void* d_ws, size_t ws_size,
                              hipStream_t stream)
{
    const float* fatoms = (const float*)d_in[0];
    const float* fbonds = (const float*)d_in[1];
    const int*   agraph = (const int*)d_in[2];
    const int*   bgraph = (const int*)d_in[3];
    const int*   mol_ids = (const int*)d_in[4];
    const float* W_i = (const float*)d_in[7];
    const float* W_h = (const float*)d_in[8];
    const float* W_o = (const float*)d_in[9];
    const float* b_o = (const float*)d_in[10];

    const int N = in_sizes[0] / 39;       // 100000
    const int E = in_sizes[1] / 50;       // 200001
    const int N_MOLS = 1000;
    const int DEPTH = 6;

    // workspace layout (bytes); all section sizes are multiples of 16
    const size_t q_sz  = (size_t)E * 256;            // u8 messages [E][256]
    const size_t sc_sz = (size_t)E * 4 * 4;          // fp32 scales [E][4]
    const size_t fb_sz = (size_t)E * 64 * 2;         // bf16 FB [E][64]
    const size_t ah_sz = (size_t)N * HID * 2;        // bf16 atom_hiddens [N][256]
    const size_t wbh_sz = (size_t)256 * 320 * 2;
    const size_t wbi_sz = (size_t)256 * 64 * 2;
    const size_t wbo_sz = (size_t)256 * 320 * 2;
    const size_t need = 2 * q_sz + 2 * sc_sz + fb_sz + ah_sz + wbh_sz + wbi_sz + wbo_sz;
    if (ws_size < need) return;

    u8* p = (u8*)d_ws;
    u8*    q0  = p;             p += q_sz;
    u8*    q1  = p;             p += q_sz;
    float* sc0 = (float*)p;     p += sc_sz;
    float* sc1 = (float*)p;     p += sc_sz;
    u16*   FB  = (u16*)p;       p += fb_sz;
    u16*   ah  = (u16*)p;       p += ah_sz;
    u16*   wbh = (u16*)p;       p += wbh_sz;
    u16*   wbi = (u16*)p;       p += wbi_sz;
    u16*   wbo = (u16*)p;

    float* out = (float*)d_out;

    build_wb<<<dim3(256), dim3(64), 0, stream>>>(W_h, 256, 0, 256, W_i, 50, 0, 50, wbh, 320);
    build_wb<<<dim3(256), dim3(64), 0, stream>>>(W_i, 50, 0, 50, W_i, 50, 0, 0, wbi, 64);
    build_wb<<<dim3(256), dim3(64), 0, stream>>>(W_o, 295, 39, 256, W_o, 295, 0, 39, wbo, 320);
    build_fb<<<dim3((E + 3) / 4), dim3(256), 0, stream>>>(fbonds, FB, E);

    const int gE = (E + 63) / 64;     // 3126
    const int gN = (N + 63) / 64;     // 1563

    // layer 0: q0 = quant(relu(FB @ W_i.T))
    fused_layer<<<dim3(gE), dim3(512), 0, stream>>>(
        nullptr, nullptr, nullptr, 0, FB, 64, 1, nullptr, 0, 0, 0,
        wbi, 64, nullptr, q0, sc0, E);

    // hidden layers (ping-pong): dst = quant(relu(gather(src)@W_h.T + fbonds@W_i.T))
    u8* src = q0;  float* ssc = sc0;
    u8* dst = q1;  float* dsc = sc1;
    for (int it = 0; it < DEPTH - 1; ++it) {
        fused_layer<<<dim3(gE), dim3(512), 0, stream>>>(
            src, ssc, bgraph, 4, FB, 64, 1, nullptr, 0, 0, 0,
            wbh, 320, nullptr, dst, dsc, E);
        u8* tq = src; src = dst; dst = tq;
        float* ts = ssc; ssc = dsc; dsc = ts;
    }
    // after 5 layers: src = q1/sc1 (final message)

    // output layer: ah = relu(gather_a(src)@W_o[:,39:].T + fatoms@W_o[:,:39].T + b_o), bf16
    fused_layer<<<dim3(gN), dim3(512), 0, stream>>>(
        src, ssc, agraph, 4, nullptr, 0, 0, fatoms, 39, 39, 1,
        wbo, 320, b_o, ah, nullptr, N);

    // per-molecule mean
    segment_mean<<<dim3(N_MOLS), dim3(256), 0, stream>>>(ah, mol_ids, out, N);
}

// Round 8
// 1202.308 us; speedup vs baseline: 2.5393x; 1.0881x over previous
//
#include <hip/hip_runtime.h>

#define HID 256
#define AS_LD 72    // u16; K-loop A-tile row stride (144 B, 16B-aligned)
#define TB_LD 264   // u16; epilogue transpose row stride (528 B, 16B-aligned)

typedef unsigned short u16;
typedef unsigned char u8;
typedef unsigned int u32;
typedef short bf16x8 __attribute__((ext_vector_type(8)));
typedef float f32x4 __attribute__((ext_vector_type(4)));
typedef u16 u16x8 __attribute__((ext_vector_type(8)));

static __device__ __forceinline__ float bf2f(u16 b) {
    u32 u = ((u32)b) << 16;
    return __uint_as_float(u);
}
static __device__ __forceinline__ u16 f2bf(float f) {
    u32 u = __float_as_uint(f);
    return (u16)((u + 0x7FFFu + ((u >> 16) & 1u)) >> 16);  // RN-even
}

// ---------------------------------------------------------------------------
// Fused gather + GEMM + relu, tile 64 rows x 256 cols, BK=64, 512 threads.
// R8: u8 messages, granularity-correct (fixes R7's 488 MB fetch):
//   - PAIR-STAGED gathers: chunks (2p,2p+1) = 128 u8 cols = ONE full 128-B
//     line per neighbor row; each thread loads uint4 (16 B), 8 thr/row cover
//     the line. Line-touches/layer: 2.4M (HALF of bf16-R5's 4.8M), 0 waste.
//     Even chunk consumed by threads g<4, odd by g>=4 (va held in regs).
//   - PER-ROW scale (fp32 [E]): loaded once per row in the preamble with
//     nbi -- kills R7's 4.8M per-chunk scattered 4-B scale txns.
// Messages: q = round(v*255/rowmax), dequant sum = sum_j s_j*q_j (linear).
// Pipeline per chunk kc (issue-order discipline, R3):
//   1. bq loads (WB B-frags, L2-hot)    <- oldest this iteration
//   2. consume(kc): counted vmcnt for its own data only (bq in flight);
//      even-gather waits pair; odd-gather is register-only (no wait)
//   3. issue next: pairs on odd kc, singles (FB/Cf) one iter ahead
//   4. s_waitcnt lgkmcnt(0) + raw s_barrier (no vmcnt drain)
//   5. ds_read af + 16 MFMAs (bq wait = counted vmcnt)
// launch_bounds (512,4): VGPR cap 128 (R4: (512,6) caps at 40 -> 1.4 GB
// scratch; R6: byte-vector transients spill too -> sequential shift/mask
// extraction, two 8-col groups to keep the live window small).
// ---------------------------------------------------------------------------
__global__ __launch_bounds__(512, 4) void fused_layer(
    const u8* __restrict__ Sg, const float* __restrict__ Ssc,
    const int* __restrict__ graph, int c1,
    const u16* __restrict__ Bd, int ldbd, int c2,
    const float* __restrict__ Cf, int ldcf, int Kc, int c3,
    const u16* __restrict__ WB, int ldw,
    const float* __restrict__ bias,
    void* __restrict__ Cout, float* __restrict__ Csc, int M)
{
    __shared__ __align__(16) u16 lds[2 * 64 * AS_LD];   // 18,432 B (union: A-dbuf / transpose)

    const int t    = threadIdx.x;
    const int w    = t >> 6;           // 0..7
    const int lane = t & 63;
    const int row0 = blockIdx.x * 64;
    const int wc   = w * 32;           // wave's 32 columns
    const int fr   = lane & 15;
    const int fq   = lane >> 4;

    const int g  = t & 7;              // granule within row
    const int ra = t >> 3;             // 0..63 -> one A row per thread
    const int gr = row0 + ra;
    const int grc = gr < M ? gr : 0;

    int nbi[6];
    float sv[6];
    const u16* bdp = nullptr;
    if (c1 > 0) {
        const int* gp = graph + (size_t)grc * 6;
        #pragma unroll
        for (int j = 0; j < 6; ++j) nbi[j] = gp[j];
        #pragma unroll
        for (int j = 0; j < 6; ++j) sv[j] = Ssc[nbi[j]];
    }
    if (c2 > 0) bdp = Bd + (size_t)grc * ldbd;

    const int nch = c1 + c2 + c3;
    const int nbf = c1 + c2;           // gather + direct-bf16 chunks

    // prefetch registers
    uint4 va[6];                       // one full 128-B pair-line slice (16 B/thread)
    u16x8 vb;                          // direct bf16 chunk
    float fa[8];                       // fp32 chunk

    // issue gather pair (kc even): full-line uint4 loads
    auto issue_pair = [&](int kc) {
        #pragma unroll
        for (int j = 0; j < 6; ++j)
            va[j] = *(const uint4*)(Sg + (size_t)nbi[j] * 256 + kc * 64 + g * 16);
    };
    // issue non-gather chunk kc
    auto issue_single = [&](int kc) {
        if (kc < nbf) {
            vb = *(const u16x8*)(bdp + (kc - c1) * 64 + g * 8);
        } else {
            const int kb = (kc - nbf) * 64 + g * 8;
            #pragma unroll
            for (int i = 0; i < 8; ++i)
                fa[i] = (gr < M && kb + i < Kc) ? Cf[(size_t)gr * ldcf + kb + i] : 0.f;
        }
    };

    // consume chunk kc -> bf16 row fragment -> LDS
    auto consume = [&](int kc, u16* Ab) {
        if (kc < c1) {
            // pair mapping: thread g holds pair-cols [g*16, g*16+16);
            // chunk kc uses threads with g>>2 == kc&1; in-chunk col (g&3)*16
            if ((g >> 2) == (kc & 1)) {
                const int cb = (g & 3) * 16;
                // group A: cols cb..cb+8 from dwords x,y
                {
                    float sa[8] = {};
                    #pragma unroll
                    for (int j = 0; j < 6; ++j) {
                        const u32 lo = va[j].x, hi = va[j].y;
                        const float s = sv[j];
                        sa[0] += (float)( lo        & 0xFFu) * s;
                        sa[1] += (float)((lo >>  8) & 0xFFu) * s;
                        sa[2] += (float)((lo >> 16) & 0xFFu) * s;
                        sa[3] += (float)( lo >> 24         ) * s;
                        sa[4] += (float)( hi        & 0xFFu) * s;
                        sa[5] += (float)((hi >>  8) & 0xFFu) * s;
                        sa[6] += (float)((hi >> 16) & 0xFFu) * s;
                        sa[7] += (float)( hi >> 24         ) * s;
                    }
                    u16 o[8];
                    #pragma unroll
                    for (int e = 0; e < 8; ++e) o[e] = f2bf(sa[e]);
                    *(uint4*)(Ab + ra * AS_LD + cb) = *(const uint4*)o;
                }
                // group B: cols cb+8..cb+16 from dwords z,w
                {
                    float sa[8] = {};
                    #pragma unroll
                    for (int j = 0; j < 6; ++j) {
                        const u32 lo = va[j].z, hi = va[j].w;
                        const float s = sv[j];
                        sa[0] += (float)( lo        & 0xFFu) * s;
                        sa[1] += (float)((lo >>  8) & 0xFFu) * s;
                        sa[2] += (float)((lo >> 16) & 0xFFu) * s;
                        sa[3] += (float)( lo >> 24         ) * s;
                        sa[4] += (float)( hi        & 0xFFu) * s;
                        sa[5] += (float)((hi >>  8) & 0xFFu) * s;
                        sa[6] += (float)((hi >> 16) & 0xFFu) * s;
                        sa[7] += (float)( hi >> 24         ) * s;
                    }
                    u16 o[8];
                    #pragma unroll
                    for (int e = 0; e < 8; ++e) o[e] = f2bf(sa[e]);
                    *(uint4*)(Ab + ra * AS_LD + cb + 8) = *(const uint4*)o;
                }
            }
        } else if (kc < nbf) {
            *(uint4*)(Ab + ra * AS_LD + g * 8) = *(const uint4*)&vb;
        } else {
            u16 o[8];
            #pragma unroll
            for (int i = 0; i < 8; ++i) o[i] = f2bf(fa[i]);
            *(uint4*)(Ab + ra * AS_LD + g * 8) = *(const uint4*)o;
        }
    };

    f32x4 acc[4][2] = {};
    if (c1 > 0) issue_pair(0);
    else if (nch > 0) issue_single(0);

    #pragma unroll 1
    for (int kc = 0; kc < nch; ++kc) {
        u16* Ab = lds + (kc & 1) * (64 * AS_LD);

        // 1. B fragments FIRST (oldest loads of this iteration)
        bf16x8 bq[2][2];
        #pragma unroll
        for (int s = 0; s < 2; ++s)
            #pragma unroll
            for (int j = 0; j < 2; ++j) {
                const int col = wc + j * 16 + fr;
                bq[s][j] = *(const bf16x8*)(WB + (size_t)col * ldw + kc * 64 + s * 32 + fq * 8);
            }

        // 2. consume chunk kc (counted wait for its data; bq in flight)
        consume(kc, Ab);

        // 3. prefetch: pairs on odd kc (after consume read old va), singles
        //    one iteration ahead; loads span barrier + compute
        {
            const int nk = kc + 1;
            if (nk < nch) {
                if (nk >= c1)            issue_single(nk);
                else if ((nk & 1) == 0)  issue_pair(nk);
            }
        }

        // 4. drain LDS writes only; global prefetch stays outstanding
        asm volatile("s_waitcnt lgkmcnt(0)" ::: "memory");
        __builtin_amdgcn_s_barrier();
        asm volatile("" ::: "memory");   // fence: no memory-op hoist above barrier

        // 5. compute: ds_read A frags + 16 MFMAs (bq wait = counted vmcnt)
        #pragma unroll
        for (int s = 0; s < 2; ++s) {
            bf16x8 af[4];
            #pragma unroll
            for (int i = 0; i < 4; ++i)
                af[i] = *(const bf16x8*)(Ab + (i * 16 + fr) * AS_LD + s * 32 + fq * 8);
            #pragma unroll
            for (int j = 0; j < 2; ++j)
                #pragma unroll
                for (int i = 0; i < 4; ++i)
                    acc[i][j] = __builtin_amdgcn_mfma_f32_16x16x32_bf16(bq[s][j], af[i], acc[i][j], 0, 0, 0);
        }
    }

    // ---- epilogue: 2-pass transpose through LDS ----
    // acc[i][j]: C-rows i*16+fr, C-cols wc + j*16 + fq*4 .. +3
    u16* Tb = lds;                          // 32 x TB_LD view
    const bool quant = (Csc != nullptr);
    #pragma unroll
    for (int s2 = 0; s2 < 2; ++s2) {
        __syncthreads();                    // K-loop / previous pass done with lds
        #pragma unroll
        for (int j = 0; j < 2; ++j) {
            const int gc = wc + j * 16 + fq * 4;
            float4 bv = make_float4(0.f, 0.f, 0.f, 0.f);
            if (bias) bv = *(const float4*)&bias[gc];
            #pragma unroll
            for (int ii = 0; ii < 2; ++ii) {
                const int i = s2 * 2 + ii;  // acc row-block
                u16 o[4];
                o[0] = f2bf(fmaxf(acc[i][j][0] + bv.x, 0.f));
                o[1] = f2bf(fmaxf(acc[i][j][1] + bv.y, 0.f));
                o[2] = f2bf(fmaxf(acc[i][j][2] + bv.z, 0.f));
                o[3] = f2bf(fmaxf(acc[i][j][3] + bv.w, 0.f));
                *(uint2*)(Tb + (ii * 16 + fr) * TB_LD + gc) = *(const uint2*)o;
            }
        }
        __syncthreads();                    // half-tile complete
        const int gsl = t & 31;             // 8-col granule within 256-col row
        const int rb  = t >> 5;             // 0..15
        #pragma unroll
        for (int it2 = 0; it2 < 2; ++it2) {
            const int rl = it2 * 16 + rb;
            const int grr = row0 + s2 * 32 + rl;
            const u16x8 v = *(const u16x8*)(Tb + rl * TB_LD + gsl * 8);
            if (quant) {
                // per-ROW linear quant: 32-lane row max via shfl tree
                float f[8];
                float mx = 0.f;
                #pragma unroll
                for (int e = 0; e < 8; ++e) { f[e] = bf2f(v[e]); mx = fmaxf(mx, f[e]); }
                mx = fmaxf(mx, __shfl_xor(mx, 1));
                mx = fmaxf(mx, __shfl_xor(mx, 2));
                mx = fmaxf(mx, __shfl_xor(mx, 4));
                mx = fmaxf(mx, __shfl_xor(mx, 8));
                mx = fmaxf(mx, __shfl_xor(mx, 16));
                const float r = mx > 0.f ? 255.f / mx : 0.f;
                u32 plo = 0, phi = 0;
                #pragma unroll
                for (int e = 0; e < 4; ++e)
                    plo |= ((u32)(f[e] * r + 0.5f)) << (8 * e);
                #pragma unroll
                for (int e = 4; e < 8; ++e)
                    phi |= ((u32)(f[e] * r + 0.5f)) << (8 * (e - 4));
                if (grr < M) {
                    uint2 qv; qv.x = plo; qv.y = phi;
                    *(uint2*)((u8*)Cout + (size_t)grr * 256 + gsl * 8) = qv;
                    if (gsl == 0)
                        Csc[grr] = mx * (1.f / 255.f);
                }
            } else {
                if (grr < M)
                    *(u16x8*)((u16*)Cout + (size_t)grr * 256 + gsl * 8) = v;
            }
        }
    }
}

// WB[n][k] bf16: k<k1 -> src1[n][off1+k]; k1<=k<k1+k2 -> src2[n][off2+k-k1]; else 0
__global__ void build_wb(const float* __restrict__ src1, int lds1, int off1, int k1,
                         const float* __restrict__ src2, int lds2, int off2, int k2,
                         u16* __restrict__ dst, int ldd)
{
    const int n = blockIdx.x;  // 0..255
    for (int k = threadIdx.x; k < ldd; k += blockDim.x) {
        float v = 0.f;
        if (k < k1)           v = src1[(size_t)n * lds1 + off1 + k];
        else if (k < k1 + k2) v = src2[(size_t)n * lds2 + off2 + (k - k1)];
        dst[(size_t)n * ldd + k] = f2bf(v);
    }
}

// FB[e][0:64] = bf16(fbonds[e][0:50]) padded with zeros
__global__ void build_fb(const float* __restrict__ fb, u16* __restrict__ FB, int E)
{
    const int e = blockIdx.x * 4 + (threadIdx.x >> 6);
    if (e >= E) return;
    const int k = threadIdx.x & 63;
    FB[(size_t)e * 64 + k] = (k < 50) ? f2bf(fb[(size_t)e * 50 + k]) : (u16)0;
}

// per-molecule mean over sorted mol_ids; atomh bf16, out fp32
__global__ void segment_mean(const u16* __restrict__ atomh, const int* __restrict__ mol_ids,
                             float* __restrict__ out, int N)
{
    const int m = blockIdx.x;
    const int t = threadIdx.x;
    __shared__ int s_lo, s_hi;
    if (t == 0) {
        int lo = 0, hi = N;
        while (lo < hi) { int mid = (lo + hi) >> 1; if (mol_ids[mid] < m) lo = mid + 1; else hi = mid; }
        s_lo = lo;
        lo = s_lo; hi = N;
        while (lo < hi) { int mid = (lo + hi) >> 1; if (mol_ids[mid] < m + 1) lo = mid + 1; else hi = mid; }
        s_hi = lo;
    }
    __syncthreads();
    const int lo = s_lo, hi = s_hi;
    float sum = 0.f;
    for (int a = lo; a < hi; ++a) sum += bf2f(atomh[(size_t)a * HID + t]);
    const float cnt = (float)((hi - lo) > 1 ? (hi - lo) : 1);
    out[(size_t)m * HID + t] = sum / cnt;
}

extern "C" void kernel_launch(void* const* d_in, const int* in_sizes, int n_in,
                              void* d_out, int out_size, void* d_ws, size_t ws_size,
                              hipStream_t stream)
{
    const float* fatoms = (const float*)d_in[0];
    const float* fbonds = (const float*)d_in[1];
    const int*   agraph = (const int*)d_in[2];
    const int*   bgraph = (const int*)d_in[3];
    const int*   mol_ids = (const int*)d_in[4];
    const float* W_i = (const float*)d_in[7];
    const float* W_h = (const float*)d_in[8];
    const float* W_o = (const float*)d_in[9];
    const float* b_o = (const float*)d_in[10];

    const int N = in_sizes[0] / 39;       // 100000
    const int E = in_sizes[1] / 50;       // 200001
    const int N_MOLS = 1000;
    const int DEPTH = 6;

    // workspace layout (bytes); all section sizes multiples of 256
    const size_t q_sz  = (size_t)E * 256;                      // u8 messages [E][256]
    const size_t sc_sz = (((size_t)E * 4) + 255) & ~(size_t)255;  // fp32 scales [E]
    const size_t fb_sz = (size_t)E * 64 * 2;                   // bf16 FB [E][64]
    const size_t ah_sz = (size_t)N * HID * 2;                  // bf16 atom_hiddens
    const size_t wbh_sz = (size_t)256 * 320 * 2;
    const size_t wbi_sz = (size_t)256 * 64 * 2;
    const size_t wbo_sz = (size_t)256 * 320 * 2;
    const size_t need = 2 * q_sz + 2 * sc_sz + fb_sz + ah_sz + wbh_sz + wbi_sz + wbo_sz;
    if (ws_size < need) return;

    u8* p = (u8*)d_ws;
    u8*    q0  = p;             p += q_sz;
    u8*    q1  = p;             p += q_sz;
    float* sc0 = (float*)p;     p += sc_sz;
    float* sc1 = (float*)p;     p += sc_sz;
    u16*   FB  = (u16*)p;       p += fb_sz;
    u16*   ah  = (u16*)p;       p += ah_sz;
    u16*   wbh = (u16*)p;       p += wbh_sz;
    u16*   wbi = (u16*)p;       p += wbi_sz;
    u16*   wbo = (u16*)p;

    float* out = (float*)d_out;

    build_wb<<<dim3(256), dim3(64), 0, stream>>>(W_h, 256, 0, 256, W_i, 50, 0, 50, wbh, 320);
    build_wb<<<dim3(256), dim3(64), 0, stream>>>(W_i, 50, 0, 50, W_i, 50, 0, 0, wbi, 64);
    build_wb<<<dim3(256), dim3(64), 0, stream>>>(W_o, 295, 39, 256, W_o, 295, 0, 39, wbo, 320);
    build_fb<<<dim3((E + 3) / 4), dim3(256), 0, stream>>>(fbonds, FB, E);

    const int gE = (E + 63) / 64;     // 3126
    const int gN = (N + 63) / 64;     // 1563

    // layer 0: q0 = quant(relu(FB @ W_i.T))
    fused_layer<<<dim3(gE), dim3(512), 0, stream>>>(
        nullptr, nullptr, nullptr, 0, FB, 64, 1, nullptr, 0, 0, 0,
        wbi, 64, nullptr, q0, sc0, E);

    // hidden layers (ping-pong): dst = quant(relu(gather(src)@W_h.T + fbonds@W_i.T))
    u8* src = q0;  float* ssc = sc0;
    u8* dst = q1;  float* dsc = sc1;
    for (int it = 0; it < DEPTH - 1; ++it) {
        fused_layer<<<dim3(gE), dim3(512), 0, stream>>>(
            src, ssc, bgraph, 4, FB, 64, 1, nullptr, 0, 0, 0,
            wbh, 320, nullptr, dst, dsc, E);
        u8* tq = src; src = dst; dst = tq;
        float* ts = ssc; ssc = dsc; dsc = ts;
    }
    // after 5 layers: src/ssc = final message

    // output layer: ah = relu(gather_a(src)@W_o[:,39:].T + fatoms@W_o[:,:39].T + b_o), bf16
    fused_layer<<<dim3(gN), dim3(512), 0, stream>>>(
        src, ssc, agraph, 4, nullptr, 0, 0, fatoms, 39, 39, 1,
        wbo, 320, b_o, ah, nullptr, N);

    // per-molecule mean
    segment_mean<<<dim3(N_MOLS), dim3(256), 0, stream>>>(ah, mol_ids, out, N);
}